// Round 1
// baseline (193.537 us; speedup 1.0000x reference)
//
#include <hip/hip_runtime.h>
#include <cstdint>
#include <cstddef>

// Problem dims
#define BB 8
#define HH 512
#define PP 512
#define LL 2048

typedef __attribute__((ext_vector_type(8))) __bf16 bf16x8;
typedef __attribute__((ext_vector_type(4))) float f32x4;

__device__ __forceinline__ uint16_t f2bf(float f) {
  uint32_t u = __builtin_bit_cast(uint32_t, f);
  u += 0x7FFFu + ((u >> 16) & 1u);   // RNE
  return (uint16_t)(u >> 16);
}

__device__ __forceinline__ void async_copy16(const void* gptr, void* ldsptr) {
  __builtin_amdgcn_global_load_lds(
      (const __attribute__((address_space(1))) unsigned int*)gptr,
      (__attribute__((address_space(3))) unsigned int*)ldsptr,
      16, 0, 0);
}

// ---------------------------------------------------------------------------
// prep: A1 (1024x512 bf16) = [B_re; B_im], A2 (512x1024 bf16) = [C_re, -C_im],
//       Dd (512 f32) = diag(D)
// ---------------------------------------------------------------------------
__global__ __launch_bounds__(256) void prep_mats(
    const float* __restrict__ Bbar, const float* __restrict__ Cri,
    const float* __restrict__ Dm,
    uint16_t* __restrict__ A1, uint16_t* __restrict__ A2,
    float* __restrict__ Dd) {
  int idx = blockIdx.x * 256 + threadIdx.x;   // 0 .. 512*512-1
  int p = idx >> 9, h = idx & 511;
  // A1[m][k]: m<512 -> Bre[p=m][k=h], m>=512 -> Bim  (coalesced in h)
  A1[(size_t)p * 512 + h]          = f2bf(Bbar[((size_t)p * 512 + h) * 2 + 0]);
  A1[(size_t)(512 + p) * 512 + h]  = f2bf(Bbar[((size_t)p * 512 + h) * 2 + 1]);
  // A2[h][k']: k'<512 -> Cre[h][p], k'>=512 -> -Cim[h][p]  (coalesced in p2)
  int h2 = idx >> 9, p2 = idx & 511;
  A2[(size_t)h2 * 1024 + p2]        = f2bf( Cri[((size_t)h2 * 512 + p2) * 2 + 0]);
  A2[(size_t)h2 * 1024 + 512 + p2]  = f2bf(-Cri[((size_t)h2 * 512 + p2) * 2 + 1]);
  if (idx < 512) Dd[idx] = Dm[(size_t)idx * 512 + idx];
}

// ---------------------------------------------------------------------------
// transpose u: (B, H=512, L=2048) f32  ->  u_t (B, L=2048, H=512) bf16
// 64x64 tiles via LDS (leading-dim pad 72 to break bank conflicts)
// ---------------------------------------------------------------------------
__global__ __launch_bounds__(256) void transpose_u_kernel(
    const float* __restrict__ U, uint16_t* __restrict__ Ut) {
  __shared__ __align__(16) uint16_t lds[64 * 72];
  const int t = threadIdx.x;
  const int b = blockIdx.z;
  const int l0 = blockIdx.x * 64, h0 = blockIdx.y * 64;
#pragma unroll
  for (int it = 0; it < 4; ++it) {
    int q = t + it * 256;            // 0..1023
    int r = q >> 4;                  // h-local
    int c4 = q & 15;                 // group of 4 l
    float4 v = *(const float4*)(U + ((size_t)(b * 512 + h0 + r)) * 2048 + l0 + c4 * 4);
    lds[(c4 * 4 + 0) * 72 + r] = f2bf(v.x);
    lds[(c4 * 4 + 1) * 72 + r] = f2bf(v.y);
    lds[(c4 * 4 + 2) * 72 + r] = f2bf(v.z);
    lds[(c4 * 4 + 3) * 72 + r] = f2bf(v.w);
  }
  __syncthreads();
#pragma unroll
  for (int it = 0; it < 2; ++it) {
    int q = t + it * 256;            // 0..511
    int r2 = q >> 3;                 // l-local
    int c8 = q & 7;                  // group of 8 h
    uint4 w = *(const uint4*)&lds[r2 * 72 + c8 * 8];
    *(uint4*)(Ut + ((size_t)(b * 2048 + l0 + r2)) * 512 + h0 + c8 * 8) = w;
  }
}

// ---------------------------------------------------------------------------
// transpose x: (B, 1024, 2048) bf16 -> x_t (B, 2048, 1024) bf16
// ---------------------------------------------------------------------------
__global__ __launch_bounds__(256) void transpose_x_kernel(
    const uint16_t* __restrict__ X, uint16_t* __restrict__ Xt) {
  __shared__ __align__(16) uint16_t lds[64 * 72];
  const int t = threadIdx.x;
  const int b = blockIdx.z;
  const int l0 = blockIdx.x * 64, k0 = blockIdx.y * 64;
#pragma unroll
  for (int it = 0; it < 2; ++it) {
    int q = t + it * 256;            // 0..511
    int r = q >> 3;                  // k-local
    int c8 = q & 7;                  // group of 8 l
    uint4 v = *(const uint4*)(X + ((size_t)(b * 1024 + k0 + r)) * 2048 + l0 + c8 * 8);
    uint32_t wv[4] = {v.x, v.y, v.z, v.w};
#pragma unroll
    for (int d = 0; d < 4; ++d) {
      lds[(c8 * 8 + d * 2 + 0) * 72 + r] = (uint16_t)(wv[d] & 0xFFFFu);
      lds[(c8 * 8 + d * 2 + 1) * 72 + r] = (uint16_t)(wv[d] >> 16);
    }
  }
  __syncthreads();
#pragma unroll
  for (int it = 0; it < 2; ++it) {
    int q = t + it * 256;
    int r2 = q >> 3;                 // l-local
    int c8 = q & 7;                  // group of 8 k
    uint4 w = *(const uint4*)&lds[r2 * 72 + c8 * 8];
    *(uint4*)(Xt + ((size_t)(b * 2048 + l0 + r2)) * 1024 + k0 + c8 * 8) = w;
  }
}

// ---------------------------------------------------------------------------
// scan: in-place on Bu (B, 1024, 2048) bf16 (rows p = re, rows 512+p = im)
// one wave per (b,p) chain; lane-local serial scan of 32 + Kogge-Stone combine
// ---------------------------------------------------------------------------
__global__ __launch_bounds__(256) void scan_kernel(
    const float* __restrict__ Lam, uint16_t* __restrict__ Bu) {
  const int gt = blockIdx.x * 256 + threadIdx.x;
  const int wave = gt >> 6, lane = gt & 63;
  const int b = wave >> 9, p = wave & 511;
  const float lr = Lam[p * 2 + 0], li = Lam[p * 2 + 1];
  // lambda^32 via 5 squarings (uniform per wave)
  float ar = lr, ai = li;
#pragma unroll
  for (int s = 0; s < 5; ++s) { float nr = ar * ar - ai * ai, ni = 2.f * ar * ai; ar = nr; ai = ni; }

  uint16_t* rowre = Bu + ((size_t)(b * 1024 + p)) * 2048 + lane * 32;
  uint16_t* rowim = Bu + ((size_t)(b * 1024 + 512 + p)) * 2048 + lane * 32;
  uint4 vr[4], vi[4];
#pragma unroll
  for (int q = 0; q < 4; ++q) { vr[q] = ((const uint4*)rowre)[q]; vi[q] = ((const uint4*)rowim)[q]; }

  float xr[32], xi[32];
  float sr = 0.f, si = 0.f;
#pragma unroll
  for (int q = 0; q < 4; ++q) {
    uint32_t wr[4] = {vr[q].x, vr[q].y, vr[q].z, vr[q].w};
    uint32_t wi[4] = {vi[q].x, vi[q].y, vi[q].z, vi[q].w};
#pragma unroll
    for (int d = 0; d < 4; ++d) {
      float br0 = __builtin_bit_cast(float, wr[d] << 16);
      float bi0 = __builtin_bit_cast(float, wi[d] << 16);
      float br1 = __builtin_bit_cast(float, wr[d] & 0xFFFF0000u);
      float bi1 = __builtin_bit_cast(float, wi[d] & 0xFFFF0000u);
      int j = q * 8 + d * 2;
      float nr = lr * sr - li * si + br0, ni = lr * si + li * sr + bi0;
      sr = nr; si = ni; xr[j] = sr; xi[j] = si;
      nr = lr * sr - li * si + br1; ni = lr * si + li * sr + bi1;
      sr = nr; si = ni; xr[j + 1] = sr; xi[j + 1] = si;
    }
  }
  // Kogge-Stone inclusive scan of (A=lambda^32, S=segment sum) over 64 lanes
  float Ar = ar, Ai = ai, Sr = sr, Si = si;
#pragma unroll
  for (int off = 1; off < 64; off <<= 1) {
    float pAr = __shfl_up(Ar, off), pAi = __shfl_up(Ai, off);
    float pSr = __shfl_up(Sr, off), pSi = __shfl_up(Si, off);
    if (lane >= off) {
      float tSr = Ar * pSr - Ai * pSi + Sr;
      float tSi = Ar * pSi + Ai * pSr + Si;
      float tAr = Ar * pAr - Ai * pAi;
      float tAi = Ar * pAi + Ai * pAr;
      Sr = tSr; Si = tSi; Ar = tAr; Ai = tAi;
    }
  }
  float Cr = __shfl_up(Sr, 1), Ci = __shfl_up(Si, 1);
  if (lane == 0) { Cr = 0.f; Ci = 0.f; }
  // apply carry: x_j += lambda^{j+1} * C
  float fr_ = lr * Cr - li * Ci, fi_ = lr * Ci + li * Cr;
#pragma unroll
  for (int j = 0; j < 32; ++j) {
    xr[j] += fr_; xi[j] += fi_;
    float nfr = fr_ * lr - fi_ * li, nfi = fr_ * li + fi_ * lr;
    fr_ = nfr; fi_ = nfi;
  }
  // pack + store (in place)
#pragma unroll
  for (int q = 0; q < 4; ++q) {
    uint32_t wr[4], wi[4];
#pragma unroll
    for (int d = 0; d < 4; ++d) {
      int j = q * 8 + d * 2;
      wr[d] = (uint32_t)f2bf(xr[j]) | ((uint32_t)f2bf(xr[j + 1]) << 16);
      wi[d] = (uint32_t)f2bf(xi[j]) | ((uint32_t)f2bf(xi[j + 1]) << 16);
    }
    ((uint4*)rowre)[q] = make_uint4(wr[0], wr[1], wr[2], wr[3]);
    ((uint4*)rowim)[q] = make_uint4(wi[0], wi[1], wi[2], wi[3]);
  }
}

// ---------------------------------------------------------------------------
// m97-style MFMA GEMM: C[M x 2048] = A[M x K] * B_t[2048 x K]^T per batch b.
// 128x128 block tile, 4 waves (2x2 of 64x64), BK=32, global_load_lds width 16.
// EPI2=false: store bf16 to Obf (M=1024 layout). EPI2=true: + diag(D)*u, GELU,
// store f32 (M=512).
// ---------------------------------------------------------------------------
template <int K, bool EPI2>
__global__ __launch_bounds__(256) void gemm_kernel(
    const uint16_t* __restrict__ A, const uint16_t* __restrict__ Bt,
    uint16_t* __restrict__ Obf, float* __restrict__ Of32,
    const float* __restrict__ Dd, const float* __restrict__ Uu) {
  __shared__ __align__(16) uint16_t Alds[128 * 32];
  __shared__ __align__(16) uint16_t Blds[128 * 32];
  const int t = threadIdx.x, lane = t & 63, w = t >> 6;
  const int m0 = blockIdx.y * 128, n0 = blockIdx.x * 128, b = blockIdx.z;

  // staging map: byte f = t*16 (+4096); row = f/64, 16B chunk = (f%64)/16
  const int ra = t >> 2;             // 0..63
  const int ca = (t & 3) * 8;        // element offset of 16B chunk
  const uint16_t* gA0 = A + (size_t)(m0 + ra) * K + ca;
  const uint16_t* gA1 = A + (size_t)(m0 + 64 + ra) * K + ca;
  const uint16_t* gB0 = Bt + ((size_t)b * 2048 + n0 + ra) * K + ca;
  const uint16_t* gB1 = Bt + ((size_t)b * 2048 + n0 + 64 + ra) * K + ca;

  f32x4 acc[4][4];
#pragma unroll
  for (int i = 0; i < 4; ++i)
#pragma unroll
    for (int j = 0; j < 4; ++j) acc[i][j] = (f32x4){0.f, 0.f, 0.f, 0.f};

  const int wm = (w >> 1) * 64, wn = (w & 1) * 64;
  const int fr = lane & 15, fq = lane >> 4;

  for (int kb = 0; kb < K; kb += 32) {
    async_copy16(gA0 + kb, Alds + t * 8);
    async_copy16(gA1 + kb, Alds + 2048 + t * 8);
    async_copy16(gB0 + kb, Blds + t * 8);
    async_copy16(gB1 + kb, Blds + 2048 + t * 8);
    __syncthreads();   // drains vmcnt -> LDS tiles visible
    bf16x8 af[4], bfr[4];
#pragma unroll
    for (int i = 0; i < 4; ++i) {
      af[i]  = *(const bf16x8*)&Alds[(wm + i * 16 + fr) * 32 + fq * 8];
      bfr[i] = *(const bf16x8*)&Blds[(wn + i * 16 + fr) * 32 + fq * 8];
    }
#pragma unroll
    for (int i = 0; i < 4; ++i)
#pragma unroll
      for (int j = 0; j < 4; ++j)
        acc[i][j] = __builtin_amdgcn_mfma_f32_16x16x32_bf16(af[i], bfr[j], acc[i][j], 0, 0, 0);
    __syncthreads();   // protect LDS from next iteration's staging
  }

  if constexpr (!EPI2) {
    uint16_t* O = Obf + ((size_t)b * 1024 + m0) * 2048 + n0;
#pragma unroll
    for (int i = 0; i < 4; ++i)
#pragma unroll
      for (int j = 0; j < 4; ++j)
#pragma unroll
        for (int r = 0; r < 4; ++r) {
          int mm = wm + i * 16 + fq * 4 + r;
          int nn = wn + j * 16 + fr;
          O[(size_t)mm * 2048 + nn] = f2bf(acc[i][j][r]);
        }
  } else {
    const size_t base = ((size_t)b * 512 + m0) * 2048 + n0;
    float* O = Of32 + base;
    const float* Ub = Uu + base;
#pragma unroll
    for (int i = 0; i < 4; ++i)
#pragma unroll
      for (int r = 0; r < 4; ++r) {
        int mm = wm + i * 16 + fq * 4 + r;
        float dv = Dd[m0 + mm];
#pragma unroll
        for (int j = 0; j < 4; ++j) {
          int nn = wn + j * 16 + fr;
          float xv = acc[i][j][r] + dv * Ub[(size_t)mm * 2048 + nn];
          O[(size_t)mm * 2048 + nn] = 0.5f * xv * (1.f + erff(xv * 0.70710678118654752f));
        }
      }
  }
}

// ---------------------------------------------------------------------------
extern "C" void kernel_launch(void* const* d_in, const int* in_sizes, int n_in,
                              void* d_out, int out_size, void* d_ws, size_t ws_size,
                              hipStream_t stream) {
  const float* u    = (const float*)d_in[0];   // (8,512,2048)
  const float* Lam  = (const float*)d_in[1];   // (512,2)
  const float* Bbar = (const float*)d_in[2];   // (512,512,2)
  const float* Cri  = (const float*)d_in[3];   // (512,512,2)
  const float* Dm   = (const float*)d_in[4];   // (512,512)
  float* out = (float*)d_out;

  char* ws = (char*)d_ws;
  // layout (bytes): Bu 33.55MB | u_t/x_t (aliased) 33.55MB | A1 1MB | A2 1MB | Dd 2KB
  uint16_t* Bu  = (uint16_t*)(ws);                       // (8,1024,2048) bf16
  uint16_t* u_t = (uint16_t*)(ws + 33554432);            // (8,2048,512)  bf16
  uint16_t* x_t = (uint16_t*)(ws + 33554432);            // (8,2048,1024) bf16 (after gemm1 done with u_t)
  uint16_t* A1  = (uint16_t*)(ws + 67108864);            // (1024,512)
  uint16_t* A2  = (uint16_t*)(ws + 68157440);            // (512,1024)
  float*    Dd  = (float*)   (ws + 69206016);            // (512)

  prep_mats<<<1024, 256, 0, stream>>>(Bbar, Cri, Dm, A1, A2, Dd);
  transpose_u_kernel<<<dim3(32, 8, BB), 256, 0, stream>>>(u, u_t);
  gemm_kernel<512, false><<<dim3(16, 8, BB), 256, 0, stream>>>(A1, u_t, Bu, nullptr, nullptr, nullptr);
  scan_kernel<<<1024, 256, 0, stream>>>(Lam, Bu);
  transpose_x_kernel<<<dim3(32, 16, BB), 256, 0, stream>>>(Bu, x_t);
  gemm_kernel<1024, true><<<dim3(16, 4, BB), 256, 0, stream>>>(A2, x_t, nullptr, out, Dd, u);
}